// Round 8
// baseline (390.225 us; speedup 1.0000x reference)
//
#include <hip/hip_runtime.h>
#include <cmath>
#include <cstring>
#include <algorithm>

// ---------------------------------------------------------------------------
// SphericalHarmonicsShellsConv  (MI355X / gfx950) — round 9
//
// Per (b,v):  y(30x256) = K^T(30x32) · G(32x256) gathered  ->  CG recombine.
//
// NEW vs round 8 (one change): all output stores PLAIN (not nontemporal).
// Evidence matrix: {NT,6blk}=W182/F81, {plain,6blk}=W183/F104,
// {NT,8blk}=W373/F207 (2x write amplification: 16B NT stores fail to merge
// into 64B lines under 8-block concurrency -> partial-sector HBM writes +
// RMW fetches). Plain stores merge in L2 regardless of timing. This round
// fills the {plain,8blk} cell, keeping the occupancy win (53->84% measured).
// Kept: bf16 Y in LDS (12,688 B -> 8 blocks/CU), 4-wide padded CG lists,
// descending-count job sort, host-built tables.
// ---------------------------------------------------------------------------

#define NB      4
#define NN      4096
#define NV      2048
#define NP      32
#define NY      30
#define YROWS   26
#define YCOLS   244          // element row stride (240 cols + 4 pad), u16 units
#define NJOBS_CG 972
#define NLISTS_MAX 4096
#define JOBS_BYTE_OFF 32768  // NLISTS_MAX * 8

typedef float        f32x4 __attribute__((ext_vector_type(4)));
typedef unsigned int u32x4 __attribute__((ext_vector_type(4)));
typedef short        s16x8 __attribute__((ext_vector_type(8)));

// ===========================================================================
// HOST-SIDE table generation (runs once; pure constant data)
// ===========================================================================
namespace shtab {

struct I2 { int x, y; };
struct I4 { int x, y, z, w; };

struct Tabs {
    I2 lists[NLISTS_MAX];  // 32768 B (padded, 4-entry-aligned lists)
    I4 jobs[NJOBS_CG];     // 15552 B  (starts at byte 32768, 16-aligned)
};
static_assert(sizeof(Tabs) == 32768 + 15552, "layout");

// ---- term tables (34 terms) -----------------------------------------------
static const int T_J[34]  = {0,0,0,0, 1,1,1,1,1,1,1,1,1, 2,2,2,2,2,2,2,2,2,2,2, 3,3,3,3,3,3,3,3,3,3};
static const int T_j[34]  = {0,1,2,3, 1,0,1,2,1,2,3,2,3, 2,0,1,2,3,1,2,3,1,2,3, 3,0,2,3,1,2,3,1,2,3};
static const int T_l[34]  = {0,1,2,3, 0,1,1,1,2,2,2,3,3, 0,2,1,1,1,2,2,2,3,3,3, 0,3,1,1,2,2,2,3,3,3};
static const int T_ch[34] = {0,64,112,144, 0,48,112,160,192,240,272,288,320,
                             0,32,96,144,176,192,240,272,288,336,368,
                             0,16,80,112,128,176,208,224,272,304};
static const int T_cg[34] = {-1,0,9,34, -1,-2,83,110,155,200,275,380,485,
                             -1,-2,632,677,752,857,932,1057,1232,1337,1512,
                             -1,-2,1757,1862,2009,2114,2289,2534,2681,2926};

static const int YOFFP[4] = {0, 0, 9, 19};    // row base in reduced Y (j>=1)
static const int COFF[4]  = {0, 16, 64, 144};
static const int WTAB[4]  = {160, 336, 384, 320};
static const int OTAB[4]  = {0, 1310720, 9568256, 25296896};

static double hfact(int n) {
    static const double F[11] = {1,1,2,6,24,120,720,5040,40320,362880,3628800};
    return F[n];
}

static double h_su2cg(int j1, int m1, int j2, int m2, int j3, int m3) {
    int vmin = -j1 + j2 + m3;
    if (-j1 + m1 > vmin) vmin = -j1 + m1;
    if (0 > vmin) vmin = 0;
    int vmax = j2 + j3 + m1;
    if (j3 - j1 + j2 < vmax) vmax = j3 - j1 + j2;
    if (j3 + m3 < vmax) vmax = j3 + m3;
    double num = (2.0 * j3 + 1.0) * hfact(j3 + j1 - j2) * hfact(j3 - j1 + j2) *
                 hfact(j1 + j2 - j3) * hfact(j3 + m3) * hfact(j3 - m3);
    double den = hfact(j1 + j2 + j3 + 1) * hfact(j1 - m1) * hfact(j1 + m1) *
                 hfact(j2 - m2) * hfact(j2 + m2);
    double C = std::sqrt(num / den);
    double S = 0.0;
    for (int v = vmin; v <= vmax; ++v) {
        double t = hfact(j2 + j3 + m1 - v) * hfact(j1 - m1 + v) /
                   (hfact(v) * hfact(j3 - j1 + j2 - v) * hfact(j3 + m3 - v) *
                    hfact(v + j1 - j2 - m3));
        S += ((v + j2 + m2) & 1) ? -t : t;
    }
    return C * S;
}

// element of (-i)^l * Q_l at (row, col)
static void h_qelem(int l, int row, int col, double* pre, double* pim) {
    int m = row - l;
    const double s2 = 0.70710678118654752440;
    double qr = 0.0, qi = 0.0;
    if (m < 0) {
        if (col == l - m) qr = s2;
        if (col == l + m) qi = -s2;
    } else if (m == 0) {
        if (col == l) qr = 1.0;
    } else {
        double sg = (m & 1) ? -1.0 : 1.0;
        if (col == l + m) qr = sg * s2;
        if (col == l - m) qi = sg * s2;
    }
    double rr, ii;
    switch (l & 3) {
        case 0:  rr = qr;  ii = qi;  break;
        case 1:  rr = qi;  ii = -qr; break;
        case 2:  rr = -qr; ii = -qi; break;
        default: rr = -qi; ii = qr;  break;
    }
    *pre = rr; *pim = ii;
}

static Tabs build_tabs() {
    Tabs T;
    std::memset(&T, 0, sizeof(T));

    static double cgws[3269];
    std::memset(cgws, 0, sizeof(cgws));

    // ---- dense real-CG tables (27 cg terms) -------------------------------
    for (int t = 0; t < 34; ++t) {
        if (T_cg[t] < 0) continue;
        int j1 = T_j[t], j2 = T_l[t], j3 = T_J[t], off = T_cg[t];
        int d1 = 2 * j1 + 1, d2 = 2 * j2 + 1, d3 = 2 * j3 + 1;
        for (int a = 0; a < d1; ++a)
            for (int b2 = 0; b2 < d2; ++b2)
                for (int cp = 0; cp < d3; ++cp) {
                    double re = 0.0;
                    for (int i = 0; i < d1; ++i)
                        for (int kk = 0; kk < d2; ++kk) {
                            int m1 = i - j1, m2 = kk - j2, m3 = m1 + m2;
                            if (m3 < -j3 || m3 > j3) continue;
                            double cg = h_su2cg(j1, m1, j2, m2, j3, m3);
                            if (cg == 0.0) continue;
                            double q1r, q1i, q2r, q2i, q3r, q3i;
                            h_qelem(j1, i, a, &q1r, &q1i);
                            h_qelem(j2, kk, b2, &q2r, &q2i);
                            h_qelem(j3, j3 + m3, cp, &q3r, &q3i);
                            q3i = -q3i;  // conj
                            double pr = q1r * q2r - q1i * q2i;
                            double pi = q1r * q2i + q1i * q2r;
                            re += (pr * q3r - pi * q3i) * cg;
                        }
                    double val = (std::fabs(re) < 1e-4) ? 0.0 : re;
                    cgws[off + (a * d2 + b2) * d3 + cp] = val;
                }
    }

    // ---- compact nnz lists, padded to 4-entry multiples -------------------
    int pbase[27 * 7];
    int pcnt[27 * 7];
    std::memset(pbase, 0, sizeof(pbase));
    std::memset(pcnt, 0, sizeof(pcnt));
    int cur = 0;
    {
        int cgIdx = -1;
        for (int t = 0; t < 34; ++t) {
            if (T_cg[t] < 0) continue;
            ++cgIdx;
            int J = T_J[t], j = T_j[t], l = T_l[t];
            int base = T_cg[t];
            int dJ = 2 * J + 1, nj = 2 * j + 1, nl = 2 * l + 1;
            for (int p = 0; p < dJ; ++p) {
                pbase[cgIdx * 7 + p] = cur;
                int cnt = 0;
                for (int n = 0; n < nj; ++n)
                    for (int m = 0; m < nl; ++m) {
                        float cf = (float)cgws[base + (n * nl + m) * dJ + p];
                        if (cf != 0.f) {
                            I2 e;
                            e.x = n * (4 - j) * YCOLS + m * 16;  // element units
                            std::memcpy(&e.y, &cf, 4);
                            T.lists[cur + cnt] = e;
                            ++cnt;
                        }
                    }
                // pad to multiple of 4 with {off=0, coef=0}
                while (cnt & 3) {
                    I2 z; z.x = 0; z.y = 0;
                    T.lists[cur + cnt] = z;
                    ++cnt;
                }
                pcnt[cgIdx * 7 + p] = cnt;
                cur += cnt;
            }
        }
    }
    // cur <= 3269 + 189*3 = 3836 <= NLISTS_MAX

    // ---- 972 cg-job records ----------------------------------------------
    for (int jid = 0; jid < NJOBS_CG; ++jid) {
        int t = 0, q = jid, cgIdx = -1;
        for (t = 0; t < 34; ++t) {
            if (T_cg[t] < 0) continue;
            ++cgIdx;
            int npt = (2 * T_J[t] + 1) * (4 - T_j[t]) * 4;
            if (q < npt) break;
            q -= npt;
        }
        int J = T_J[t], j = T_j[t], l = T_l[t];
        int rc = (4 - j) * 4;
        int p = q / rc;
        int rem = q % rc;
        int r = rem >> 2, c4 = rem & 3;
        int out_off = OTAB[J] + p * WTAB[J] + T_ch[t] + r * 16 + c4 * 4;
        int y_base = (YOFFP[j] + r) * YCOLS + (COFF[l] - 16) + c4 * 4;  // elements
        I4 jb;
        jb.x = out_off | (J << 28);
        jb.y = y_base;
        jb.z = pbase[cgIdx * 7 + p];
        jb.w = pcnt[cgIdx * 7 + p];
        T.jobs[jid] = jb;
    }

    // ---- stable sort by descending count: balances strided assignment,
    //      keeps equal-count c4-siblings adjacent (store coalescing; all
    //      groups are size-4 so 4-job alignment is preserved) ---------------
    std::stable_sort(T.jobs, T.jobs + NJOBS_CG,
                     [](const I4& a, const I4& b) { return a.w > b.w; });
    return T;
}

static const Tabs& get_tabs() {
    static Tabs T = build_tabs();   // once per process
    return T;
}

} // namespace shtab

// ===========================================================================
// DEVICE: conv kernel
// ===========================================================================

// MFMA helpers: split-bf16 (hi + residual) fragments, fp32-equivalent GEMM.
static __device__ __forceinline__ s16x8 mkfrag(unsigned d0, unsigned d1,
                                               unsigned d2, unsigned d3) {
    u32x4 t = {d0, d1, d2, d3};
    return __builtin_bit_cast(s16x8, t);
}

// 8 fp32 -> hi-bf16 frag + lo-residual-bf16 frag (truncation split; residual
// captures the rest, dropped lo*lo term is ~2^-16 relative).
static __device__ __forceinline__ void split8(const float* v, s16x8* hi, s16x8* lo) {
    unsigned hd[4], ld[4];
#pragma unroll
    for (int i = 0; i < 4; ++i) {
        unsigned u0 = __float_as_uint(v[2 * i]);
        unsigned u1 = __float_as_uint(v[2 * i + 1]);
        unsigned h0 = u0 & 0xffff0000u;
        unsigned h1 = u1 & 0xffff0000u;
        float l0 = v[2 * i]     - __uint_as_float(h0);
        float l1 = v[2 * i + 1] - __uint_as_float(h1);
        hd[i] = (u0 >> 16) | h1;
        ld[i] = (__float_as_uint(l0) >> 16) | (__float_as_uint(l1) & 0xffff0000u);
    }
    *hi = mkfrag(hd[0], hd[1], hd[2], hd[3]);
    *lo = mkfrag(ld[0], ld[1], ld[2], ld[3]);
}

static __device__ __forceinline__ f32x4 MFMA(s16x8 a, s16x8 b, f32x4 c) {
    return __builtin_amdgcn_mfma_f32_16x16x32_bf16(a, b, c, 0, 0, 0);
}

static __device__ __forceinline__ unsigned short f2bf(float x) {   // RNE
    unsigned u = __float_as_uint(x);
    return (unsigned short)((u + 0x7fffu + ((u >> 16) & 1u)) >> 16);
}

// conv kernel: D(256x32) = G^T(256x32) · Kpad(32x32), tiled 16x16x32.
// Tile m covers channels [16m,16m+16); wave w owns m in [4w,4w+4).
// Lane (g=lane>>4, li=lane&15):
//   A frag (G^T): row c = 16m+li, k-slot e -> p = 4g+(e&3) + (e>=4 ? 16 : 0)
//   B frag (Kpad): col r = 16nt+li, same k-slot map (A/B symmetric => any
//                  k bijection is valid as long as both sides use it)
//   D: lane holds channels cb..cb+3 (cb=16m+4g) at y-row r=16nt+li (f32x4).
__global__ __launch_bounds__(256, 8) void sh_conv_kernel(
    const float* __restrict__ x0, const float* __restrict__ x1,
    const float* __restrict__ x2, const float* __restrict__ x3,
    const int* __restrict__ pidx, const float* __restrict__ kern,
    const int2* __restrict__ lists, const int4* __restrict__ jobs,
    float* __restrict__ out) {
    __shared__ __align__(8) unsigned short Y16[YROWS * YCOLS];  // 12688 B

    const int bv   = blockIdx.x;
    const int tid  = threadIdx.x;
    const int w    = tid >> 6;
    const int lane = tid & 63;
    const int g    = lane >> 4;
    const int li   = lane & 15;

    const float* kb = kern + (size_t)bv * (NP * NY);
    const int*   pp = pidx + (size_t)bv * (NP * 2);

    // gather row index per k-slot (shared by all 4 tiles of this wave)
    int rows[8];
#pragma unroll
    for (int e = 0; e < 8; ++e) {
        int p = 4 * g + (e & 3) + ((e >= 4) ? 16 : 0);
        int2 pr = ((const int2*)pp)[p];
        rows[e] = pr.x * NN + pr.y;
    }

    // ---- B fragments (Kpad), rows 30/31 zero-padded ----
    s16x8 Bhi[2], Blo[2];
#pragma unroll
    for (int nt = 0; nt < 2; ++nt) {
        int rr = nt * 16 + li;
        float kv[8];
#pragma unroll
        for (int e = 0; e < 8; ++e) {
            int p = 4 * g + (e & 3) + ((e >= 4) ? 16 : 0);
            kv[e] = (rr < NY) ? kb[p * NY + rr] : 0.f;
        }
        split8(kv, &Bhi[nt], &Blo[nt]);
    }

    const int sJ0 = bv * 160, sJ1 = bv * 1008, sJ2 = bv * 1920, sJ3 = bv * 2240;

    // ---- per-tile: gather A, 6 MFMAs (3-way split x 2 nt), fused epilogue ---
#pragma unroll
    for (int m = 0; m < 16; ++m) {
        if ((m >> 2) != w) continue;   // wave-uniform guard (compile-time m)

        const float* src; int strd;
        if (m == 0)     { src = x0 + li;                  strd = 16;  }
        else if (m < 4) { src = x1 + (16 * m + li - 16);  strd = 48;  }
        else if (m < 9) { src = x2 + (16 * m + li - 64);  strd = 80;  }
        else            { src = x3 + (16 * m + li - 144); strd = 112; }

        float gv[8];
#pragma unroll
        for (int e = 0; e < 8; ++e)
            gv[e] = src[(size_t)rows[e] * strd];

        s16x8 Ahi, Alo;
        split8(gv, &Ahi, &Alo);

        f32x4 a0 = {0.f, 0.f, 0.f, 0.f};
        f32x4 a1 = {0.f, 0.f, 0.f, 0.f};
        a0 = MFMA(Ahi, Bhi[0], a0);
        a0 = MFMA(Ahi, Blo[0], a0);
        a0 = MFMA(Alo, Bhi[0], a0);
        a1 = MFMA(Ahi, Bhi[1], a1);
        a1 = MFMA(Ahi, Blo[1], a1);
        a1 = MFMA(Alo, Bhi[1], a1);

        const int cb = 16 * m + 4 * g;   // 4 consecutive channels per lane
#pragma unroll
        for (int nt = 0; nt < 2; ++nt) {
            f32x4 v = nt ? a1 : a0;
            int r = 16 * nt + li;        // y-row
            if (m == 0) {
                // l0 copies: channels 0..15, all 30 rows, fp32 exact-path
                if (r < NY) {
                    int ot, sj, wt, p, rr2;
                    if (r < 4)       { ot = 0;        sj = sJ0; wt = 160; p = 0;      rr2 = r; }
                    else if (r < 13) { int t = r - 4;  ot = 1310720; sj = sJ1; wt = 336;
                                       p = t / 3;  rr2 = t - 3 * (t / 3); }
                    else if (r < 23) { int t = r - 13; ot = 9568256; sj = sJ2; wt = 384;
                                       p = t >> 1; rr2 = t & 1; }
                    else             { ot = 25296896; sj = sJ3; wt = 320; p = r - 23; rr2 = 0; }
                    float* ob = out + (size_t)ot + sj + p * wt + rr2 * 16 + cb;
                    *(f32x4*)ob = v;
                }
            } else {
                if (r < 4) {
                    // j0 copies: rows 0..3, channels >= 16 (class compile-time per m)
                    const int ot = (m < 4) ? 1310720 : (m < 9 ? 9568256 : 25296896);
                    const int wt = (m < 4) ? 336 : (m < 9 ? 384 : 320);
                    const int cj = (m < 4) ? 48  : (m < 9 ? 32  : 16);
                    const int co = (m < 4) ? 16  : (m < 9 ? 64  : 144);
                    const int sj = (m < 4) ? sJ1 : (m < 9 ? sJ2 : sJ3);
                    int rel = cb - co;
                    float* ob = out + (size_t)ot + sj + (rel >> 4) * wt + cj +
                                (rel & 15) + r * 16;
                    *(f32x4*)ob = v;
                } else if (r < NY) {
                    // y rows 4..29, cols 16..255 -> LDS bf16 (one b64 write)
                    uint2 u;
                    u.x = (unsigned)f2bf(v.x) | ((unsigned)f2bf(v.y) << 16);
                    u.y = (unsigned)f2bf(v.z) | ((unsigned)f2bf(v.w) << 16);
                    *(uint2*)&Y16[(r - 4) * YCOLS + (cb - 16)] = u;
                }
            }
        }
    }

    __syncthreads();

    // ---- cg jobs: one output float4 each; lists padded to 4-entry multiples,
    //      processed 4-wide (2x int4 list loads + 4 independent LDS b64) -----
    for (int jid = tid; jid < NJOBS_CG; jid += 256) {
        int4 jb = jobs[jid];
        int J = ((unsigned)jb.x) >> 28;
        int out_off = jb.x & 0x0FFFFFFF;
        int bvoff = (J < 2) ? (J == 0 ? sJ0 : sJ1) : (J == 2 ? sJ2 : sJ3);
        const int2* lp = lists + jb.z;
        const unsigned short* yb = &Y16[jb.y];
        f32x4 s = {0.f, 0.f, 0.f, 0.f};
        for (int e = 0; e < jb.w; e += 4) {
            int4 t0 = *(const int4*)(lp + e);       // entries e, e+1
            int4 t1 = *(const int4*)(lp + e + 2);   // entries e+2, e+3
            uint2 u0 = *(const uint2*)(yb + t0.x);
            uint2 u1 = *(const uint2*)(yb + t0.z);
            uint2 u2 = *(const uint2*)(yb + t1.x);
            uint2 u3 = *(const uint2*)(yb + t1.z);
            float c0 = __int_as_float(t0.y);
            float c1 = __int_as_float(t0.w);
            float c2 = __int_as_float(t1.y);
            float c3 = __int_as_float(t1.w);
            s.x = fmaf(c0, __uint_as_float(u0.x << 16), s.x);
            s.y = fmaf(c0, __uint_as_float(u0.x & 0xffff0000u), s.y);
            s.z = fmaf(c0, __uint_as_float(u0.y << 16), s.z);
            s.w = fmaf(c0, __uint_as_float(u0.y & 0xffff0000u), s.w);
            s.x = fmaf(c1, __uint_as_float(u1.x << 16), s.x);
            s.y = fmaf(c1, __uint_as_float(u1.x & 0xffff0000u), s.y);
            s.z = fmaf(c1, __uint_as_float(u1.y << 16), s.z);
            s.w = fmaf(c1, __uint_as_float(u1.y & 0xffff0000u), s.w);
            s.x = fmaf(c2, __uint_as_float(u2.x << 16), s.x);
            s.y = fmaf(c2, __uint_as_float(u2.x & 0xffff0000u), s.y);
            s.z = fmaf(c2, __uint_as_float(u2.y << 16), s.z);
            s.w = fmaf(c2, __uint_as_float(u2.y & 0xffff0000u), s.w);
            s.x = fmaf(c3, __uint_as_float(u3.x << 16), s.x);
            s.y = fmaf(c3, __uint_as_float(u3.x & 0xffff0000u), s.y);
            s.z = fmaf(c3, __uint_as_float(u3.y << 16), s.z);
            s.w = fmaf(c3, __uint_as_float(u3.y & 0xffff0000u), s.w);
        }
        *(f32x4*)(out + (size_t)out_off + bvoff) = s;
    }
}

// ---------------------------------------------------------------------------
extern "C" void kernel_launch(void* const* d_in, const int* in_sizes, int n_in,
                              void* d_out, int out_size, void* d_ws, size_t ws_size,
                              hipStream_t stream) {
    const float* x0 = (const float*)d_in[0];
    const float* x1 = (const float*)d_in[1];
    const float* x2 = (const float*)d_in[2];
    const float* x3 = (const float*)d_in[3];
    const int* pidx = (const int*)d_in[4];
    const float* kern = (const float*)d_in[5];

    // host-built constant tables -> workspace (single small async copy)
    const shtab::Tabs& T = shtab::get_tabs();
    hipMemcpyAsync(d_ws, &T, sizeof(shtab::Tabs), hipMemcpyHostToDevice, stream);

    const int2* lists = (const int2*)d_ws;
    const int4* jobs  = (const int4*)((const char*)d_ws + JOBS_BYTE_OFF);

    sh_conv_kernel<<<NB * NV, 256, 0, stream>>>(x0, x1, x2, x3, pidx, kern,
                                                lists, jobs, (float*)d_out);
}

// Round 9
// 300.220 us; speedup vs baseline: 1.2998x; 1.2998x over previous
//
#include <hip/hip_runtime.h>
#include <cmath>
#include <cstring>
#include <algorithm>

// ---------------------------------------------------------------------------
// SphericalHarmonicsShellsConv  (MI355X / gfx950) — round 10
//
// Per (b,v):  y(30x256) = K^T(30x32) · G(32x256) gathered  ->  CG recombine.
//
// Occupancy evidence matrix closed in r8/r9: 8 blocks/CU doubles HBM traffic
// (W 183->378, F 104->230; L2 thrash: partial-sector write evictions + gather
// reuse collapse) regardless of store flavor. 6-block regime is optimal.
//
// NEW vs round 7 (one change): m-loop split into LOAD phase (all 32 scattered
// gathers issued into gv[4][8] registers) + COMPUTE phase (split8 + MFMA +
// epilogue). r7's VGPR=40 proved the compiler serialized 4 gather-latency
// exposures per wave; this forces 1. VGPR ~72 <= 85 (6 waves/SIMD budget).
// Kept from r7: fp32 Y in LDS (25.6 KB -> exactly 6 blocks/CU), plain stores,
// 4-wide padded CG lists, descending-count job sort, host-built tables.
// ---------------------------------------------------------------------------

#define NB      4
#define NN      4096
#define NV      2048
#define NP      32
#define NY      30
#define YROWS   26
#define YCOLS   244          // element row stride (240 cols + 4 pad)
#define NJOBS_CG 972
#define NLISTS_MAX 4096
#define JOBS_BYTE_OFF 32768  // NLISTS_MAX * 8

typedef float        f32x4 __attribute__((ext_vector_type(4)));
typedef unsigned int u32x4 __attribute__((ext_vector_type(4)));
typedef short        s16x8 __attribute__((ext_vector_type(8)));

// ===========================================================================
// HOST-SIDE table generation (runs once; pure constant data)
// ===========================================================================
namespace shtab {

struct I2 { int x, y; };
struct I4 { int x, y, z, w; };

struct Tabs {
    I2 lists[NLISTS_MAX];  // 32768 B (padded, 4-entry-aligned lists)
    I4 jobs[NJOBS_CG];     // 15552 B  (starts at byte 32768, 16-aligned)
};
static_assert(sizeof(Tabs) == 32768 + 15552, "layout");

// ---- term tables (34 terms) -----------------------------------------------
static const int T_J[34]  = {0,0,0,0, 1,1,1,1,1,1,1,1,1, 2,2,2,2,2,2,2,2,2,2,2, 3,3,3,3,3,3,3,3,3,3};
static const int T_j[34]  = {0,1,2,3, 1,0,1,2,1,2,3,2,3, 2,0,1,2,3,1,2,3,1,2,3, 3,0,2,3,1,2,3,1,2,3};
static const int T_l[34]  = {0,1,2,3, 0,1,1,1,2,2,2,3,3, 0,2,1,1,1,2,2,2,3,3,3, 0,3,1,1,2,2,2,3,3,3};
static const int T_ch[34] = {0,64,112,144, 0,48,112,160,192,240,272,288,320,
                             0,32,96,144,176,192,240,272,288,336,368,
                             0,16,80,112,128,176,208,224,272,304};
static const int T_cg[34] = {-1,0,9,34, -1,-2,83,110,155,200,275,380,485,
                             -1,-2,632,677,752,857,932,1057,1232,1337,1512,
                             -1,-2,1757,1862,2009,2114,2289,2534,2681,2926};

static const int YOFFP[4] = {0, 0, 9, 19};    // row base in reduced Y (j>=1)
static const int COFF[4]  = {0, 16, 64, 144};
static const int WTAB[4]  = {160, 336, 384, 320};
static const int OTAB[4]  = {0, 1310720, 9568256, 25296896};

static double hfact(int n) {
    static const double F[11] = {1,1,2,6,24,120,720,5040,40320,362880,3628800};
    return F[n];
}

static double h_su2cg(int j1, int m1, int j2, int m2, int j3, int m3) {
    int vmin = -j1 + j2 + m3;
    if (-j1 + m1 > vmin) vmin = -j1 + m1;
    if (0 > vmin) vmin = 0;
    int vmax = j2 + j3 + m1;
    if (j3 - j1 + j2 < vmax) vmax = j3 - j1 + j2;
    if (j3 + m3 < vmax) vmax = j3 + m3;
    double num = (2.0 * j3 + 1.0) * hfact(j3 + j1 - j2) * hfact(j3 - j1 + j2) *
                 hfact(j1 + j2 - j3) * hfact(j3 + m3) * hfact(j3 - m3);
    double den = hfact(j1 + j2 + j3 + 1) * hfact(j1 - m1) * hfact(j1 + m1) *
                 hfact(j2 - m2) * hfact(j2 + m2);
    double C = std::sqrt(num / den);
    double S = 0.0;
    for (int v = vmin; v <= vmax; ++v) {
        double t = hfact(j2 + j3 + m1 - v) * hfact(j1 - m1 + v) /
                   (hfact(v) * hfact(j3 - j1 + j2 - v) * hfact(j3 + m3 - v) *
                    hfact(v + j1 - j2 - m3));
        S += ((v + j2 + m2) & 1) ? -t : t;
    }
    return C * S;
}

// element of (-i)^l * Q_l at (row, col)
static void h_qelem(int l, int row, int col, double* pre, double* pim) {
    int m = row - l;
    const double s2 = 0.70710678118654752440;
    double qr = 0.0, qi = 0.0;
    if (m < 0) {
        if (col == l - m) qr = s2;
        if (col == l + m) qi = -s2;
    } else if (m == 0) {
        if (col == l) qr = 1.0;
    } else {
        double sg = (m & 1) ? -1.0 : 1.0;
        if (col == l + m) qr = sg * s2;
        if (col == l - m) qi = sg * s2;
    }
    double rr, ii;
    switch (l & 3) {
        case 0:  rr = qr;  ii = qi;  break;
        case 1:  rr = qi;  ii = -qr; break;
        case 2:  rr = -qr; ii = -qi; break;
        default: rr = -qi; ii = qr;  break;
    }
    *pre = rr; *pim = ii;
}

static Tabs build_tabs() {
    Tabs T;
    std::memset(&T, 0, sizeof(T));

    static double cgws[3269];
    std::memset(cgws, 0, sizeof(cgws));

    // ---- dense real-CG tables (27 cg terms) -------------------------------
    for (int t = 0; t < 34; ++t) {
        if (T_cg[t] < 0) continue;
        int j1 = T_j[t], j2 = T_l[t], j3 = T_J[t], off = T_cg[t];
        int d1 = 2 * j1 + 1, d2 = 2 * j2 + 1, d3 = 2 * j3 + 1;
        for (int a = 0; a < d1; ++a)
            for (int b2 = 0; b2 < d2; ++b2)
                for (int cp = 0; cp < d3; ++cp) {
                    double re = 0.0;
                    for (int i = 0; i < d1; ++i)
                        for (int kk = 0; kk < d2; ++kk) {
                            int m1 = i - j1, m2 = kk - j2, m3 = m1 + m2;
                            if (m3 < -j3 || m3 > j3) continue;
                            double cg = h_su2cg(j1, m1, j2, m2, j3, m3);
                            if (cg == 0.0) continue;
                            double q1r, q1i, q2r, q2i, q3r, q3i;
                            h_qelem(j1, i, a, &q1r, &q1i);
                            h_qelem(j2, kk, b2, &q2r, &q2i);
                            h_qelem(j3, j3 + m3, cp, &q3r, &q3i);
                            q3i = -q3i;  // conj
                            double pr = q1r * q2r - q1i * q2i;
                            double pi = q1r * q2i + q1i * q2r;
                            re += (pr * q3r - pi * q3i) * cg;
                        }
                    double val = (std::fabs(re) < 1e-4) ? 0.0 : re;
                    cgws[off + (a * d2 + b2) * d3 + cp] = val;
                }
    }

    // ---- compact nnz lists, padded to 4-entry multiples -------------------
    int pbase[27 * 7];
    int pcnt[27 * 7];
    std::memset(pbase, 0, sizeof(pbase));
    std::memset(pcnt, 0, sizeof(pcnt));
    int cur = 0;
    {
        int cgIdx = -1;
        for (int t = 0; t < 34; ++t) {
            if (T_cg[t] < 0) continue;
            ++cgIdx;
            int J = T_J[t], j = T_j[t], l = T_l[t];
            int base = T_cg[t];
            int dJ = 2 * J + 1, nj = 2 * j + 1, nl = 2 * l + 1;
            for (int p = 0; p < dJ; ++p) {
                pbase[cgIdx * 7 + p] = cur;
                int cnt = 0;
                for (int n = 0; n < nj; ++n)
                    for (int m = 0; m < nl; ++m) {
                        float cf = (float)cgws[base + (n * nl + m) * dJ + p];
                        if (cf != 0.f) {
                            I2 e;
                            e.x = n * (4 - j) * YCOLS + m * 16;  // element units
                            std::memcpy(&e.y, &cf, 4);
                            T.lists[cur + cnt] = e;
                            ++cnt;
                        }
                    }
                // pad to multiple of 4 with {off=0, coef=0}
                while (cnt & 3) {
                    I2 z; z.x = 0; z.y = 0;
                    T.lists[cur + cnt] = z;
                    ++cnt;
                }
                pcnt[cgIdx * 7 + p] = cnt;
                cur += cnt;
            }
        }
    }
    // cur <= 3269 + 189*3 = 3836 <= NLISTS_MAX

    // ---- 972 cg-job records ----------------------------------------------
    for (int jid = 0; jid < NJOBS_CG; ++jid) {
        int t = 0, q = jid, cgIdx = -1;
        for (t = 0; t < 34; ++t) {
            if (T_cg[t] < 0) continue;
            ++cgIdx;
            int npt = (2 * T_J[t] + 1) * (4 - T_j[t]) * 4;
            if (q < npt) break;
            q -= npt;
        }
        int J = T_J[t], j = T_j[t], l = T_l[t];
        int rc = (4 - j) * 4;
        int p = q / rc;
        int rem = q % rc;
        int r = rem >> 2, c4 = rem & 3;
        int out_off = OTAB[J] + p * WTAB[J] + T_ch[t] + r * 16 + c4 * 4;
        int y_base = (YOFFP[j] + r) * YCOLS + (COFF[l] - 16) + c4 * 4;  // elements
        I4 jb;
        jb.x = out_off | (J << 28);
        jb.y = y_base;
        jb.z = pbase[cgIdx * 7 + p];
        jb.w = pcnt[cgIdx * 7 + p];
        T.jobs[jid] = jb;
    }

    // ---- stable sort by descending count: balances strided assignment,
    //      keeps equal-count c4-siblings adjacent (store coalescing; classes
    //      are unions of complete 4-groups so 4-alignment is preserved) -----
    std::stable_sort(T.jobs, T.jobs + NJOBS_CG,
                     [](const I4& a, const I4& b) { return a.w > b.w; });
    return T;
}

static const Tabs& get_tabs() {
    static Tabs T = build_tabs();   // once per process
    return T;
}

} // namespace shtab

// ===========================================================================
// DEVICE: conv kernel
// ===========================================================================

// MFMA helpers: split-bf16 (hi + residual) fragments, fp32-equivalent GEMM.
static __device__ __forceinline__ s16x8 mkfrag(unsigned d0, unsigned d1,
                                               unsigned d2, unsigned d3) {
    u32x4 t = {d0, d1, d2, d3};
    return __builtin_bit_cast(s16x8, t);
}

// 8 fp32 -> hi-bf16 frag + lo-residual-bf16 frag (truncation split; residual
// captures the rest, dropped lo*lo term is ~2^-16 relative).
static __device__ __forceinline__ void split8(const float* v, s16x8* hi, s16x8* lo) {
    unsigned hd[4], ld[4];
#pragma unroll
    for (int i = 0; i < 4; ++i) {
        unsigned u0 = __float_as_uint(v[2 * i]);
        unsigned u1 = __float_as_uint(v[2 * i + 1]);
        unsigned h0 = u0 & 0xffff0000u;
        unsigned h1 = u1 & 0xffff0000u;
        float l0 = v[2 * i]     - __uint_as_float(h0);
        float l1 = v[2 * i + 1] - __uint_as_float(h1);
        hd[i] = (u0 >> 16) | h1;
        ld[i] = (__float_as_uint(l0) >> 16) | (__float_as_uint(l1) & 0xffff0000u);
    }
    *hi = mkfrag(hd[0], hd[1], hd[2], hd[3]);
    *lo = mkfrag(ld[0], ld[1], ld[2], ld[3]);
}

static __device__ __forceinline__ f32x4 MFMA(s16x8 a, s16x8 b, f32x4 c) {
    return __builtin_amdgcn_mfma_f32_16x16x32_bf16(a, b, c, 0, 0, 0);
}

// conv kernel: D(256x32) = G^T(256x32) · Kpad(32x32), tiled 16x16x32.
// Tile m covers channels [16m,16m+16); wave w owns m in [4w,4w+4).
// Lane (g=lane>>4, li=lane&15):
//   A frag (G^T): row c = 16m+li, k-slot e -> p = 4g+(e&3) + (e>=4 ? 16 : 0)
//   B frag (Kpad): col r = 16nt+li, same k-slot map (A/B symmetric => any
//                  k bijection is valid as long as both sides use it)
//   D: lane holds channels cb..cb+3 (cb=16m+4g) at y-row r=16nt+li (f32x4).
__global__ __launch_bounds__(256, 6) void sh_conv_kernel(
    const float* __restrict__ x0, const float* __restrict__ x1,
    const float* __restrict__ x2, const float* __restrict__ x3,
    const int* __restrict__ pidx, const float* __restrict__ kern,
    const int2* __restrict__ lists, const int4* __restrict__ jobs,
    float* __restrict__ out) {
    __shared__ __align__(16) float Y[YROWS * YCOLS];  // 25376 B, fp32 -> 6 blk/CU

    const int bv   = blockIdx.x;
    const int tid  = threadIdx.x;
    const int w    = tid >> 6;
    const int lane = tid & 63;
    const int g    = lane >> 4;
    const int li   = lane & 15;

    const float* kb = kern + (size_t)bv * (NP * NY);
    const int*   pp = pidx + (size_t)bv * (NP * 2);

    // gather row index per k-slot (shared by all 4 tiles of this wave)
    int rows[8];
#pragma unroll
    for (int e = 0; e < 8; ++e) {
        int p = 4 * g + (e & 3) + ((e >= 4) ? 16 : 0);
        int2 pr = ((const int2*)pp)[p];
        rows[e] = pr.x * NN + pr.y;
    }

    // ---- B fragments (Kpad), rows 30/31 zero-padded ----
    s16x8 Bhi[2], Blo[2];
#pragma unroll
    for (int nt = 0; nt < 2; ++nt) {
        int rr = nt * 16 + li;
        float kv[8];
#pragma unroll
        for (int e = 0; e < 8; ++e) {
            int p = 4 * g + (e & 3) + ((e >= 4) ? 16 : 0);
            kv[e] = (rr < NY) ? kb[p * NY + rr] : 0.f;
        }
        split8(kv, &Bhi[nt], &Blo[nt]);
    }

    const int sJ0 = bv * 160, sJ1 = bv * 1008, sJ2 = bv * 1920, sJ3 = bv * 2240;

    // ---- PHASE 1: issue ALL 32 scattered gathers (one latency exposure) ----
    // gv[k][e] for the wave's 4 tiles m = 4w+k; statically indexed (full
    // unroll) so it stays in registers (+32 VGPR, ~72 total <= 85 budget).
    float gv[4][8];
#pragma unroll
    for (int m = 0; m < 16; ++m) {
        if ((m >> 2) != w) continue;   // wave-uniform guard (compile-time m)

        const float* src; int strd;
        if (m == 0)     { src = x0 + li;                  strd = 16;  }
        else if (m < 4) { src = x1 + (16 * m + li - 16);  strd = 48;  }
        else if (m < 9) { src = x2 + (16 * m + li - 64);  strd = 80;  }
        else            { src = x3 + (16 * m + li - 144); strd = 112; }

#pragma unroll
        for (int e = 0; e < 8; ++e)
            gv[m & 3][e] = src[(size_t)rows[e] * strd];
    }

    // ---- PHASE 2: split8 + 6 MFMAs + fused epilogue per tile ---------------
#pragma unroll
    for (int m = 0; m < 16; ++m) {
        if ((m >> 2) != w) continue;

        s16x8 Ahi, Alo;
        split8(gv[m & 3], &Ahi, &Alo);

        f32x4 a0 = {0.f, 0.f, 0.f, 0.f};
        f32x4 a1 = {0.f, 0.f, 0.f, 0.f};
        a0 = MFMA(Ahi, Bhi[0], a0);
        a0 = MFMA(Ahi, Blo[0], a0);
        a0 = MFMA(Alo, Bhi[0], a0);
        a1 = MFMA(Ahi, Bhi[1], a1);
        a1 = MFMA(Ahi, Blo[1], a1);
        a1 = MFMA(Alo, Bhi[1], a1);

        const int cb = 16 * m + 4 * g;   // 4 consecutive channels per lane
#pragma unroll
        for (int nt = 0; nt < 2; ++nt) {
            f32x4 v = nt ? a1 : a0;
            int r = 16 * nt + li;        // y-row
            if (m == 0) {
                // l0 copies: channels 0..15, all 30 rows, fp32 exact-path
                if (r < NY) {
                    int ot, sj, wt, p, rr2;
                    if (r < 4)       { ot = 0;        sj = sJ0; wt = 160; p = 0;      rr2 = r; }
                    else if (r < 13) { int t = r - 4;  ot = 1310720; sj = sJ1; wt = 336;
                                       p = t / 3;  rr2 = t - 3 * (t / 3); }
                    else if (r < 23) { int t = r - 13; ot = 9568256; sj = sJ2; wt = 384;
                                       p = t >> 1; rr2 = t & 1; }
                    else             { ot = 25296896; sj = sJ3; wt = 320; p = r - 23; rr2 = 0; }
                    float* ob = out + (size_t)ot + sj + p * wt + rr2 * 16 + cb;
                    *(f32x4*)ob = v;
                }
            } else {
                if (r < 4) {
                    // j0 copies: rows 0..3, channels >= 16 (class compile-time per m)
                    const int ot = (m < 4) ? 1310720 : (m < 9 ? 9568256 : 25296896);
                    const int wt = (m < 4) ? 336 : (m < 9 ? 384 : 320);
                    const int cj = (m < 4) ? 48  : (m < 9 ? 32  : 16);
                    const int co = (m < 4) ? 16  : (m < 9 ? 64  : 144);
                    const int sj = (m < 4) ? sJ1 : (m < 9 ? sJ2 : sJ3);
                    int rel = cb - co;
                    float* ob = out + (size_t)ot + sj + (rel >> 4) * wt + cj +
                                (rel & 15) + r * 16;
                    *(f32x4*)ob = v;
                } else if (r < NY) {
                    // y rows 4..29, cols 16..255 -> LDS fp32 (one b128 write)
                    *(f32x4*)&Y[(r - 4) * YCOLS + (cb - 16)] = v;
                }
            }
        }
    }

    __syncthreads();

    // ---- cg jobs: one output float4 each; lists padded to 4-entry multiples,
    //      processed 4-wide (2x int4 list loads + 4 independent LDS b128) ----
    for (int jid = tid; jid < NJOBS_CG; jid += 256) {
        int4 jb = jobs[jid];
        int J = ((unsigned)jb.x) >> 28;
        int out_off = jb.x & 0x0FFFFFFF;
        int bvoff = (J < 2) ? (J == 0 ? sJ0 : sJ1) : (J == 2 ? sJ2 : sJ3);
        const int2* lp = lists + jb.z;
        const float* yb = &Y[jb.y];
        f32x4 s = {0.f, 0.f, 0.f, 0.f};
        for (int e = 0; e < jb.w; e += 4) {
            int4 t0 = *(const int4*)(lp + e);       // entries e, e+1
            int4 t1 = *(const int4*)(lp + e + 2);   // entries e+2, e+3
            f32x4 y0 = *(const f32x4*)(yb + t0.x);
            f32x4 y1 = *(const f32x4*)(yb + t0.z);
            f32x4 y2 = *(const f32x4*)(yb + t1.x);
            f32x4 y3 = *(const f32x4*)(yb + t1.z);
            float c0 = __int_as_float(t0.y);
            float c1 = __int_as_float(t0.w);
            float c2 = __int_as_float(t1.y);
            float c3 = __int_as_float(t1.w);
            s.x = fmaf(c0, y0.x, s.x);
            s.y = fmaf(c0, y0.y, s.y);
            s.z = fmaf(c0, y0.z, s.z);
            s.w = fmaf(c0, y0.w, s.w);
            s.x = fmaf(c1, y1.x, s.x);
            s.y = fmaf(c1, y1.y, s.y);
            s.z = fmaf(c1, y1.z, s.z);
            s.w = fmaf(c1, y1.w, s.w);
            s.x = fmaf(c2, y2.x, s.x);
            s.y = fmaf(c2, y2.y, s.y);
            s.z = fmaf(c2, y2.z, s.z);
            s.w = fmaf(c2, y2.w, s.w);
            s.x = fmaf(c3, y3.x, s.x);
            s.y = fmaf(c3, y3.y, s.y);
            s.z = fmaf(c3, y3.z, s.z);
            s.w = fmaf(c3, y3.w, s.w);
        }
        *(f32x4*)(out + (size_t)out_off + bvoff) = s;
    }
}

// ---------------------------------------------------------------------------
extern "C" void kernel_launch(void* const* d_in, const int* in_sizes, int n_in,
                              void* d_out, int out_size, void* d_ws, size_t ws_size,
                              hipStream_t stream) {
    const float* x0 = (const float*)d_in[0];
    const float* x1 = (const float*)d_in[1];
    const float* x2 = (const float*)d_in[2];
    const float* x3 = (const float*)d_in[3];
    const int* pidx = (const int*)d_in[4];
    const float* kern = (const float*)d_in[5];

    // host-built constant tables -> workspace (single small async copy)
    const shtab::Tabs& T = shtab::get_tabs();
    hipMemcpyAsync(d_ws, &T, sizeof(shtab::Tabs), hipMemcpyHostToDevice, stream);

    const int2* lists = (const int2*)d_ws;
    const int4* jobs  = (const int4*)((const char*)d_ws + JOBS_BYTE_OFF);

    sh_conv_kernel<<<NB * NV, 256, 0, stream>>>(x0, x1, x2, x3, pidx, kern,
                                                lists, jobs, (float*)d_out);
}